// Round 1
// baseline (539.729 us; speedup 1.0000x reference)
//
#include <hip/hip_runtime.h>

#define LDS_AS __attribute__((address_space(3)))
#define GLB_AS __attribute__((address_space(1)))

typedef __attribute__((ext_vector_type(8))) short bf16x8;
typedef __attribute__((ext_vector_type(4))) float f32x4;

static __device__ __forceinline__ unsigned short f2bf(float x) {
  union { float f; unsigned u; } c; c.f = x;
  unsigned r = c.u + 0x7fffu + ((c.u >> 16) & 1u);
  return (unsigned short)(r >> 16);
}

// ---------------- convert A fp32 -> bf16 ----------------
__global__ __launch_bounds__(256) void k_convert(const float* __restrict__ A,
                                                 unsigned short* __restrict__ Abf) {
  const long long n4 = (8192LL * 8192LL) / 4;
  long long i = (long long)blockIdx.x * blockDim.x + threadIdx.x;
  const long long stride = (long long)gridDim.x * blockDim.x;
  const float4* A4 = (const float4*)A;
  ushort4* O4 = (ushort4*)Abf;
  for (; i < n4; i += stride) {
    float4 v = A4[i];
    ushort4 o;
    o.x = f2bf(v.x); o.y = f2bf(v.y); o.z = f2bf(v.z); o.w = f2bf(v.w);
    O4[i] = o;
  }
}

// ---------------- g1t[n][m] = (X @ W1.T)^T, bf16 ----------------
__global__ __launch_bounds__(256) void k_first(const float* __restrict__ X,
                                               const float* __restrict__ W1,
                                               unsigned short* __restrict__ G1t) {
  __shared__ float Ws[32][32];
  const int t = threadIdx.x;
  for (int i = t; i < 1024; i += 256) Ws[i >> 5][i & 31] = W1[i];
  __syncthreads();
  const int m = blockIdx.x * 256 + t;
  float x[32];
  const float4* Xr = (const float4*)(X + (size_t)m * 32);
#pragma unroll
  for (int i = 0; i < 8; ++i) {
    float4 v = Xr[i];
    x[4 * i] = v.x; x[4 * i + 1] = v.y; x[4 * i + 2] = v.z; x[4 * i + 3] = v.w;
  }
#pragma unroll
  for (int n = 0; n < 32; ++n) {
    float acc = 0.f;
#pragma unroll
    for (int k = 0; k < 32; ++k) acc += x[k] * Ws[n][k];
    G1t[(size_t)n * 8192 + m] = f2bf(acc);
  }
}

// ---------------- big GEMM: P[ks] = A[:, kchunk] @ G[kchunk, :] ----------------
// Abf row-major [8192][8192] bf16, Gt transposed [D][8192] bf16,
// P fp32 [SPLITK][8192][D]. BM=32, BK=64, 256 threads (4 waves), grid (256, 4).
template <int D>
__global__ __launch_bounds__(256) void k_big(const unsigned short* __restrict__ Abf,
                                             const unsigned short* __restrict__ Gt,
                                             float* __restrict__ P) {
  constexpr int BM = 32, BK = 64;
  constexpr int A_SZ = BM * BK;   // 2048 ushorts (4KB)
  constexpr int G_SZ = D * BK;    // ushorts
  constexpr int NT = D / 32;      // n-tiles per wave (16-wide each)
  constexpr int KCH = 8192 / 4;   // per-split K chunk
  constexpr int NSTEP = KCH / BK; // 32
  __shared__ unsigned short lds[2][A_SZ + G_SZ];

  const int t = threadIdx.x;
  const int wave = t >> 6;
  const int lane = t & 63;
  const int m0 = blockIdx.x * BM;
  const int kbase = blockIdx.y * KCH;

  // stage one (A, Gt) K-tile into lds[buf]; swizzle: 16B slot s of row r holds
  // global slot (s ^ (r&7)) so swizzled ds_read is conflict-free.
  auto stage = [&](int buf, int k0) {
    {
      int r = t >> 3, s = t & 7;
      const unsigned short* src =
          Abf + (size_t)(m0 + r) * 8192 + k0 + ((s ^ (r & 7)) << 3);
      __builtin_amdgcn_global_load_lds((const GLB_AS void*)src,
                                       (LDS_AS void*)&lds[buf][wave * 512], 16, 0, 0);
    }
#pragma unroll
    for (int i = 0; i < (D * 8) / 256; ++i) {
      int slot = t + i * 256;
      int r = slot >> 3, s = slot & 7;
      const unsigned short* src =
          Gt + (size_t)r * 8192 + k0 + ((s ^ (r & 7)) << 3);
      __builtin_amdgcn_global_load_lds(
          (const GLB_AS void*)src,
          (LDS_AS void*)&lds[buf][A_SZ + (i * 256 + wave * 64) * 8], 16, 0, 0);
    }
  };

  f32x4 acc[NT];
#pragma unroll
  for (int i = 0; i < NT; ++i) acc[i] = (f32x4){0.f, 0.f, 0.f, 0.f};

  const int mt = wave & 1;            // M 16-row half
  const int ntb = (wave >> 1) * NT;   // first n-tile
  const int lr = lane & 15, lk = lane >> 4;

  stage(0, kbase);
  __syncthreads();
  for (int s = 0; s < NSTEP; ++s) {
    const int cur = s & 1;
    if (s + 1 < NSTEP) stage(cur ^ 1, kbase + (s + 1) * BK);
    const unsigned short* buf = lds[cur];
#pragma unroll
    for (int kk = 0; kk < 2; ++kk) {
      const int arow = mt * 16 + lr;
      const int slot = kk * 4 + lk;
      bf16x8 af = *(const bf16x8*)&buf[arow * 64 + ((slot ^ (arow & 7)) << 3)];
#pragma unroll
      for (int i = 0; i < NT; ++i) {
        const int n = (ntb + i) * 16 + lr;
        bf16x8 bg = *(const bf16x8*)&buf[A_SZ + n * 64 + ((slot ^ (n & 7)) << 3)];
        acc[i] = __builtin_amdgcn_mfma_f32_16x16x32_bf16(af, bg, acc[i], 0, 0, 0);
      }
    }
    __syncthreads();
  }

  // partial write: C/D layout col=lane&15, row=(lane>>4)*4+j (m89-verified)
  float* pw = P + (size_t)blockIdx.y * 8192 * D + (size_t)(m0 + mt * 16) * D;
#pragma unroll
  for (int i = 0; i < NT; ++i) {
#pragma unroll
    for (int j = 0; j < 4; ++j) {
      int row = (lane >> 4) * 4 + j;
      int col = (ntb + i) * 16 + (lane & 15);
      pw[(size_t)row * D + col] = acc[i][j];
    }
  }
}

// ---------------- epilogue: h=relu(sum partials); Gt_next = (h @ W.T)^T bf16 ----
template <int D_IN, int D_OUT>
__global__ __launch_bounds__(256) void k_epi(const float* __restrict__ P,
                                             const float* __restrict__ W,
                                             unsigned short* __restrict__ Gtn) {
  __shared__ float h[64][D_IN + 1];
  __shared__ float Ws[D_OUT][D_IN];
  const int t = threadIdx.x;
  for (int i = t; i < D_OUT * D_IN; i += 256) Ws[i / D_IN][i % D_IN] = W[i];
  const int m0 = blockIdx.x * 64;
  for (int i = t; i < (64 * D_IN) / 4; i += 256) {
    int row = (i * 4) / D_IN;
    int c = (i * 4) % D_IN;
    const float* base = P + (size_t)(m0 + row) * D_IN + c;
    float4 s = *(const float4*)base;
#pragma unroll
    for (int ks = 1; ks < 4; ++ks) {
      float4 v = *(const float4*)(base + (size_t)ks * 8192 * D_IN);
      s.x += v.x; s.y += v.y; s.z += v.z; s.w += v.w;
    }
    h[row][c] = fmaxf(s.x, 0.f);
    h[row][c + 1] = fmaxf(s.y, 0.f);
    h[row][c + 2] = fmaxf(s.z, 0.f);
    h[row][c + 3] = fmaxf(s.w, 0.f);
  }
  __syncthreads();
  const int ml = t & 63, q = t >> 6;
#pragma unroll
  for (int n2 = q * (D_OUT / 4); n2 < (q + 1) * (D_OUT / 4); ++n2) {
    float acc = 0.f;
#pragma unroll
    for (int k = 0; k < D_IN; ++k) acc += h[ml][k] * Ws[n2][k];
    Gtn[(size_t)n2 * 8192 + m0 + ml] = f2bf(acc);
  }
}

// ---------------- final: out = sum of partials (fp32) ----------------
__global__ __launch_bounds__(256) void k_final(const float* __restrict__ P,
                                               float* __restrict__ out) {
  const int i = blockIdx.x * 256 + threadIdx.x;  // 65536 float4s total
  const long long q = 8192LL * 32 / 4;
  const float4* P4 = (const float4*)P;
  float4 s = P4[i];
#pragma unroll
  for (int ks = 1; ks < 4; ++ks) {
    float4 v = P4[i + ks * q];
    s.x += v.x; s.y += v.y; s.z += v.z; s.w += v.w;
  }
  ((float4*)out)[i] = s;
}

extern "C" void kernel_launch(void* const* d_in, const int* in_sizes, int n_in,
                              void* d_out, int out_size, void* d_ws, size_t ws_size,
                              hipStream_t stream) {
  const float* A = (const float*)d_in[0];
  const float* X = (const float*)d_in[1];
  const float* W1 = (const float*)d_in[2];
  const float* W2 = (const float*)d_in[3];
  const float* W3 = (const float*)d_in[4];
  const float* W4 = (const float*)d_in[5];
  float* out = (float*)d_out;

  // ws layout
  const size_t ABF_OFF = 0;                         // 8192*8192*2 = 134217728
  const size_t GA_OFF = 134217728;                  // 64*8192*2 = 1048576
  const size_t GB_OFF = GA_OFF + 1048576;
  const size_t P_OFF = GB_OFF + 1048576;            // 4*8192*64*4 = 8388608
  const size_t NEEDED = P_OFF + 8388608;            // ~138 MB
  if (ws_size < NEEDED) return;  // cannot run fast path; fail loudly via absmax

  char* ws = (char*)d_ws;
  unsigned short* Abf = (unsigned short*)(ws + ABF_OFF);
  unsigned short* Ga = (unsigned short*)(ws + GA_OFF);
  unsigned short* Gb = (unsigned short*)(ws + GB_OFF);
  float* P = (float*)(ws + P_OFF);

  k_convert<<<2048, 256, 0, stream>>>(A, Abf);
  k_first<<<32, 256, 0, stream>>>(X, W1, Ga);            // g1t [32][8192]
  k_big<32><<<dim3(256, 4), 256, 0, stream>>>(Abf, Ga, P);
  k_epi<32, 64><<<128, 256, 0, stream>>>(P, W2, Gb);     // g2t [64][8192]
  k_big<64><<<dim3(256, 4), 256, 0, stream>>>(Abf, Gb, P);
  k_epi<64, 64><<<128, 256, 0, stream>>>(P, W3, Ga);     // g3t [64][8192]
  k_big<64><<<dim3(256, 4), 256, 0, stream>>>(Abf, Ga, P);
  k_epi<64, 32><<<128, 256, 0, stream>>>(P, W4, Gb);     // g4t [32][8192]
  k_big<32><<<dim3(256, 4), 256, 0, stream>>>(Abf, Gb, P);
  k_final<<<256, 256, 0, stream>>>(P, out);
}